// Round 22
// baseline (169.068 us; speedup 1.0000x reference)
//
#include <hip/hip_runtime.h>
#include <hip/hip_bf16.h>

// StyledConv: B=8, Cin=Cout=64, H=W=256, S=512, K=3
#define BB   8
#define CC   64
#define HH   256
#define WW   256
#define SS   512
#define HW   (HH*WW)

#define LIN_SCALE  0.044194173824159216f   // 1/sqrt(512)
#define CONV_SCALE 0.041666666666666664f   // 1/24
#define LRELU      0.2f
#define GAIN       1.4142135623730951f

// block region: 8 rows x 32 cols, processed as TWO 4-row halves (dbuf LDS)
#define TY 8
#define HY 4
#define TX 32
#define LYH (HY + 2)  // 6
#define LX (TX + 2)   // 34
#define XSE (8 * LYH * LX * 8)      // 13056 elems (26112 B) per buffer
#define WLE (9 * 8 * 64 * 8)        // weight elems per image

typedef __attribute__((ext_vector_type(8)))  short short8;     // A/B frag (8 bf16)
typedef __attribute__((ext_vector_type(16))) float floatx16;   // 32x32 C/D frag

static __device__ __forceinline__ unsigned short f2bf(float f) {
    unsigned u = __float_as_uint(f);
    u += 0x7FFF + ((u >> 16) & 1);          // RNE (inputs finite)
    return (unsigned short)(u >> 16);
}

// packed f32x2 -> bf16x2 (v_cvt_pk_bf16_f32): low = a, high = b
static __device__ __forceinline__ unsigned pk2(float a, float b) {
    __hip_bfloat162 h = __float22bfloat162_rn(make_float2(a, b));
    return *(unsigned*)&h;
}

#define VC(vv,kk) ((kk)==0?(vv).x:((kk)==1?(vv).y:((kk)==2?(vv).z:(vv).w)))

// ---------------- Kernel A ----------------
__global__ void mod_kernel(const float* __restrict__ style,
                           const float* __restrict__ mod_w,
                           const float* __restrict__ mod_b,
                           float* __restrict__ s_out) {
    __shared__ float part[256];
    int b = blockIdx.x;
    int t = threadIdx.x;
    int ci = t & 63, kp = t >> 6;
    const float* st = style + b * SS + kp * 128;
    float acc = 0.f;
    for (int k = 0; k < 128; ++k)
        acc = fmaf(st[k], mod_w[(kp * 128 + k) * CC + ci], acc);
    part[t] = acc;
    __syncthreads();
    if (t < 64) {
        float v = part[t] + part[t + 64] + part[t + 128] + part[t + 192];
        s_out[b * CC + t] = v * LIN_SCALE + mod_b[t];
    }
}

// ---------------- Kernel B: weights -> wbf[b][ko 9][g 8][co 64][j 8] ----------------
__global__ void wmod_kernel(const float* __restrict__ weight,
                            const float* __restrict__ s_in,
                            unsigned short* __restrict__ wbf) {
    int bc = blockIdx.x;                // b*64 + co
    int b = bc >> 6, co = bc & 63;
    int ci = threadIdx.x;               // one wave
    float wv[9];
    float sv = s_in[b * CC + ci] * CONV_SCALE;
    float sum = 0.f;
    const float* wp = weight + (co * CC + ci) * 9;
#pragma unroll
    for (int k = 0; k < 9; ++k) {
        wv[k] = wp[k] * sv;
        sum = fmaf(wv[k], wv[k], sum);
    }
#pragma unroll
    for (int off = 32; off; off >>= 1)
        sum += __shfl_xor(sum, off);
    float demod = rsqrtf(sum + 1e-8f);
    int g = ci >> 3, j = ci & 7;
#pragma unroll
    for (int ko = 0; ko < 9; ++ko) {
        size_t idx = ((((size_t)b * 9 + ko) * 8 + g) * 64 + co) * 8 + j;
        wbf[idx] = f2bf(wv[ko] * demod);
    }
}

// ---------------- Kernel C: implicit-GEMM conv, MFMA 32x32x16 bf16
// 256 thr (4 waves). Block owns 8 rows x 32 px, as two 4-row halves with
// double-buffered LDS. Half1's global loads issue BEFORE half0's compute
// (T14 async-STAGE split); ds_write lands after. Wave wv -> 1 row per half.
// A-frags from global wbf (depth-2 ring); B-frags contiguous from LDS.
__global__ __launch_bounds__(256, 2) void conv_kernel(
        const float* __restrict__ x,
        const float* __restrict__ noise,
        const float* __restrict__ nwp,
        const float* __restrict__ bias,
        const unsigned short* __restrict__ wbf,
        float* __restrict__ out) {
    __shared__ unsigned short xs[2][XSE];   // 52224 B

    // bijective XCD swizzle: XCD c -> batch image b=c (256 blocks per image)
    const int lin  = blockIdx.x;                 // 0..2047
    const int lin2 = (lin & 7) * 256 + (lin >> 3);
    const int b   = lin2 >> 8;
    const int rem = lin2 & 255;
    const int by  = rem >> 3;      // 0..31
    const int bx  = rem & 7;       // 0..7
    const int x0t = bx * TX;
    const int y0t = by * TY;

    const int t = threadIdx.x;
    const int lane = t & 63;
    const int wv = t >> 6;         // wave 0..3 -> row within half
    const int n31 = lane & 31;
    const int h   = lane >> 5;     // k-slice half

    // task decode for a 480-task half stage (g 8, yl 6, q 10; q fastest)
    const int na = t < 479 ? t : 479;
    const int nb = (t + 256) < 479 ? (t + 256) : 479;
    const int qa = na % 10, ra = na / 10, yla = ra % 6, ga = ra / 6;
    const int qb = nb % 10, rb = nb / 10, ylb = rb % 6, gb = rb / 6;
    const int gx0a = x0t - 4 + qa * 4, gx0b = x0t - 4 + qb * 4;
    const int gx0ca = gx0a < 0 ? 0 : (gx0a > WW - 4 ? WW - 4 : gx0a);
    const int gx0cb = gx0b < 0 ? 0 : (gx0b > WW - 4 ? WW - 4 : gx0b);

    // ---- early prefetch: A-ring + noise (independent of staging)
    const unsigned short* wb = wbf + (size_t)b * WLE;
#define ALOAD(ko, kc, m) \
    (*(const short8*)&wb[((((ko) * 8 + (kc) * 2 + h) * 64) + (m) * 32 + n31) * 8])
    short8 a0c = ALOAD(0, 0, 0), a1c = ALOAD(0, 0, 1);
    short8 a0n = ALOAD(0, 1, 0), a1n = ALOAD(0, 1, 1);
    const float nw = nwp[0];
    float nz0 = noise[(size_t)b * HW + (size_t)(y0t + wv)      * WW + x0t + n31];
    float nz1 = noise[(size_t)b * HW + (size_t)(y0t + 4 + wv)  * WW + x0t + n31];
    __builtin_amdgcn_sched_barrier(0);

    // ---- stage half0 into xs[0] (batched: 16 loads in flight)
    {
        const int y0h = y0t;
        int gya = y0h + yla - 1, gyb = y0h + ylb - 1;
        bool rowoka = (unsigned)gya < (unsigned)HH;
        bool rowokb = (unsigned)gyb < (unsigned)HH;
        int gyca = gya < 0 ? 0 : (gya > HH - 1 ? HH - 1 : gya);
        int gycb = gyb < 0 ? 0 : (gyb > HH - 1 ? HH - 1 : gyb);
        const float* xpa = x + ((size_t)b * CC + ga * 8) * HW + (size_t)gyca * WW + gx0ca;
        const float* xpb = x + ((size_t)b * CC + gb * 8) * HW + (size_t)gycb * WW + gx0cb;
        float4 va[8], vb2[8];
#pragma unroll
        for (int j = 0; j < 8; ++j) va[j]  = *(const float4*)(xpa + (size_t)j * HW);
#pragma unroll
        for (int j = 0; j < 8; ++j) vb2[j] = *(const float4*)(xpb + (size_t)j * HW);
        __builtin_amdgcn_sched_barrier(0);
#pragma unroll
        for (int k = 0; k < 4; ++k) {
            int lx = 4 * qa - 3 + k;
            if ((unsigned)lx < (unsigned)LX) {
                bool ok = rowoka && ((unsigned)(gx0a + k) < (unsigned)WW);
                uint4 w;
                w.x = ok ? pk2(VC(va[0], k), VC(va[1], k)) : 0u;
                w.y = ok ? pk2(VC(va[2], k), VC(va[3], k)) : 0u;
                w.z = ok ? pk2(VC(va[4], k), VC(va[5], k)) : 0u;
                w.w = ok ? pk2(VC(va[6], k), VC(va[7], k)) : 0u;
                *(uint4*)&xs[0][((ga * LYH + yla) * LX + lx) * 8] = w;
            }
        }
#pragma unroll
        for (int k = 0; k < 4; ++k) {
            int lx = 4 * qb - 3 + k;
            if ((unsigned)lx < (unsigned)LX) {
                bool ok = rowokb && ((unsigned)(gx0b + k) < (unsigned)WW);
                uint4 w;
                w.x = ok ? pk2(VC(vb2[0], k), VC(vb2[1], k)) : 0u;
                w.y = ok ? pk2(VC(vb2[2], k), VC(vb2[3], k)) : 0u;
                w.z = ok ? pk2(VC(vb2[4], k), VC(vb2[5], k)) : 0u;
                w.w = ok ? pk2(VC(vb2[6], k), VC(vb2[7], k)) : 0u;
                *(uint4*)&xs[0][((gb * LYH + ylb) * LX + lx) * 8] = w;
            }
        }
    }
    __syncthreads();

    // ---- issue half1 loads NOW (latency hides under half0 compute)
    const int y1h = y0t + HY;
    int gya1 = y1h + yla - 1, gyb1 = y1h + ylb - 1;
    bool rowoka1 = (unsigned)gya1 < (unsigned)HH;
    bool rowokb1 = (unsigned)gyb1 < (unsigned)HH;
    int gyca1 = gya1 < 0 ? 0 : (gya1 > HH - 1 ? HH - 1 : gya1);
    int gycb1 = gyb1 < 0 ? 0 : (gyb1 > HH - 1 ? HH - 1 : gyb1);
    {
        const float* xpa = x + ((size_t)b * CC + ga * 8) * HW + (size_t)gyca1 * WW + gx0ca;
        const float* xpb = x + ((size_t)b * CC + gb * 8) * HW + (size_t)gycb1 * WW + gx0cb;
        float4 wa[8], wb2[8];
#pragma unroll
        for (int j = 0; j < 8; ++j) wa[j]  = *(const float4*)(xpa + (size_t)j * HW);
#pragma unroll
        for (int j = 0; j < 8; ++j) wb2[j] = *(const float4*)(xpb + (size_t)j * HW);
        __builtin_amdgcn_sched_barrier(0);   // loads pinned above compute

        // ---- compute half0 from xs[0]
        floatx16 acc[2];
        acc[0] = (floatx16)0.f; acc[1] = (floatx16)0.f;
#pragma unroll
        for (int ko = 0; ko < 9; ++ko) {
            const int kh = ko / 3, kw = ko % 3;
#pragma unroll
            for (int kc = 0; kc < 4; ++kc) {
                short8 p0 = a0n, p1 = a1n;
                {
                    int s2 = ko * 4 + kc + 2;
                    if (s2 <= 35) {
                        int pko = s2 >> 2, pkc = s2 & 3;
                        p0 = ALOAD(pko, pkc, 0);
                        p1 = ALOAD(pko, pkc, 1);
                    }
                }
                const int g = kc * 2 + h;
                int ys = wv + kh;
                short8 bv = *(const short8*)&xs[0][((g * LYH + ys) * LX + kw + n31) * 8];
                __builtin_amdgcn_s_setprio(1);
                acc[0] = __builtin_amdgcn_mfma_f32_32x32x16_bf16(a0c, bv, acc[0], 0, 0, 0);
                acc[1] = __builtin_amdgcn_mfma_f32_32x32x16_bf16(a1c, bv, acc[1], 0, 0, 0);
                __builtin_amdgcn_s_setprio(0);
                a0c = a0n; a1c = a1n;
                a0n = p0;  a1n = p1;
            }
        }
        __builtin_amdgcn_sched_barrier(0);   // keep converts below compute

        // ---- convert + ds_write half1 into xs[1]
#pragma unroll
        for (int k = 0; k < 4; ++k) {
            int lx = 4 * qa - 3 + k;
            if ((unsigned)lx < (unsigned)LX) {
                bool ok = rowoka1 && ((unsigned)(gx0a + k) < (unsigned)WW);
                uint4 w;
                w.x = ok ? pk2(VC(wa[0], k), VC(wa[1], k)) : 0u;
                w.y = ok ? pk2(VC(wa[2], k), VC(wa[3], k)) : 0u;
                w.z = ok ? pk2(VC(wa[4], k), VC(wa[5], k)) : 0u;
                w.w = ok ? pk2(VC(wa[6], k), VC(wa[7], k)) : 0u;
                *(uint4*)&xs[1][((ga * LYH + yla) * LX + lx) * 8] = w;
            }
        }
#pragma unroll
        for (int k = 0; k < 4; ++k) {
            int lx = 4 * qb - 3 + k;
            if ((unsigned)lx < (unsigned)LX) {
                bool ok = rowokb1 && ((unsigned)(gx0b + k) < (unsigned)WW);
                uint4 w;
                w.x = ok ? pk2(VC(wb2[0], k), VC(wb2[1], k)) : 0u;
                w.y = ok ? pk2(VC(wb2[2], k), VC(wb2[3], k)) : 0u;
                w.z = ok ? pk2(VC(wb2[4], k), VC(wb2[5], k)) : 0u;
                w.w = ok ? pk2(VC(wb2[6], k), VC(wb2[7], k)) : 0u;
                *(uint4*)&xs[1][((gb * LYH + ylb) * LX + lx) * 8] = w;
            }
        }

        // ---- epilogue half0
        {
            int py = y0t + wv;
            float nz = nw * nz0;
#pragma unroll
            for (int reg = 0; reg < 16; ++reg) {
                int cr = (reg & 3) + 8 * (reg >> 2) + 4 * h;
                float v0 = acc[0][reg] + nz + bias[cr];
                v0 = (v0 > 0.f ? v0 : LRELU * v0) * GAIN;
                out[((size_t)b * CC + cr) * HW + (size_t)py * WW + x0t + n31] = v0;
                float v1 = acc[1][reg] + nz + bias[32 + cr];
                v1 = (v1 > 0.f ? v1 : LRELU * v1) * GAIN;
                out[((size_t)b * CC + 32 + cr) * HW + (size_t)py * WW + x0t + n31] = v1;
            }
        }
    }
    __syncthreads();

    // ---- compute half1 from xs[1]
    {
        short8 b0c = ALOAD(0, 0, 0), b1c = ALOAD(0, 0, 1);
        short8 b0n = ALOAD(0, 1, 0), b1n = ALOAD(0, 1, 1);
        floatx16 acc[2];
        acc[0] = (floatx16)0.f; acc[1] = (floatx16)0.f;
#pragma unroll
        for (int ko = 0; ko < 9; ++ko) {
            const int kh = ko / 3, kw = ko % 3;
#pragma unroll
            for (int kc = 0; kc < 4; ++kc) {
                short8 p0 = b0n, p1 = b1n;
                {
                    int s2 = ko * 4 + kc + 2;
                    if (s2 <= 35) {
                        int pko = s2 >> 2, pkc = s2 & 3;
                        p0 = ALOAD(pko, pkc, 0);
                        p1 = ALOAD(pko, pkc, 1);
                    }
                }
                const int g = kc * 2 + h;
                int ys = wv + kh;
                short8 bv = *(const short8*)&xs[1][((g * LYH + ys) * LX + kw + n31) * 8];
                __builtin_amdgcn_s_setprio(1);
                acc[0] = __builtin_amdgcn_mfma_f32_32x32x16_bf16(b0c, bv, acc[0], 0, 0, 0);
                acc[1] = __builtin_amdgcn_mfma_f32_32x32x16_bf16(b1c, bv, acc[1], 0, 0, 0);
                __builtin_amdgcn_s_setprio(0);
                b0c = b0n; b1c = b1n;
                b0n = p0;  b1n = p1;
            }
        }

        // ---- epilogue half1
        int py = y1h + wv;
        float nz = nw * nz1;
#pragma unroll
        for (int reg = 0; reg < 16; ++reg) {
            int cr = (reg & 3) + 8 * (reg >> 2) + 4 * h;
            float v0 = acc[0][reg] + nz + bias[cr];
            v0 = (v0 > 0.f ? v0 : LRELU * v0) * GAIN;
            out[((size_t)b * CC + cr) * HW + (size_t)py * WW + x0t + n31] = v0;
            float v1 = acc[1][reg] + nz + bias[32 + cr];
            v1 = (v1 > 0.f ? v1 : LRELU * v1) * GAIN;
            out[((size_t)b * CC + 32 + cr) * HW + (size_t)py * WW + x0t + n31] = v1;
        }
    }
#undef ALOAD
}

extern "C" void kernel_launch(void* const* d_in, const int* in_sizes, int n_in,
                              void* d_out, int out_size, void* d_ws, size_t ws_size,
                              hipStream_t stream) {
    const float* x       = (const float*)d_in[0];
    const float* style   = (const float*)d_in[1];
    const float* noise   = (const float*)d_in[2];
    const float* weight  = (const float*)d_in[3];
    const float* mod_w   = (const float*)d_in[4];
    const float* mod_b   = (const float*)d_in[5];
    const float* nw      = (const float*)d_in[6];
    const float* bias    = (const float*)d_in[7];
    float* out = (float*)d_out;

    float* s_buf          = (float*)d_ws;                          // 2 KB
    unsigned short* wbf   = (unsigned short*)((char*)d_ws + 4096); // 576 KB

    mod_kernel<<<dim3(BB), dim3(256), 0, stream>>>(style, mod_w, mod_b, s_buf);
    wmod_kernel<<<dim3(BB * CC), dim3(CC), 0, stream>>>(weight, s_buf, wbf);
    conv_kernel<<<dim3((WW / TX) * (HH / TY) * BB), dim3(256), 0, stream>>>(
        x, noise, nw, bias, wbf, out);
}

// Round 23
// 87.329 us; speedup vs baseline: 1.9360x; 1.9360x over previous
//
#include <hip/hip_runtime.h>
#include <hip/hip_bf16.h>

// StyledConv: B=8, Cin=Cout=64, H=W=256, S=512, K=3
#define BB   8
#define CC   64
#define HH   256
#define WW   256
#define SS   512
#define HW   (HH*WW)

#define LIN_SCALE  0.044194173824159216f   // 1/sqrt(512)
#define CONV_SCALE 0.041666666666666664f   // 1/24
#define LRELU      0.2f
#define GAIN       1.4142135623730951f

// conv tile: 8 rows x 32 cols out, all 64 co, all 64 ci staged once
#define TY 8
#define TX 32
#define LY (TY + 2)   // 10
#define LX (TX + 2)   // 34
#define WLE (9 * 8 * 64 * 8)        // weight elems per image

typedef __attribute__((ext_vector_type(8)))  short short8;     // A/B frag (8 bf16)
typedef __attribute__((ext_vector_type(16))) float floatx16;   // 32x32 C/D frag

static __device__ __forceinline__ unsigned short f2bf(float f) {
    unsigned u = __float_as_uint(f);
    u += 0x7FFF + ((u >> 16) & 1);          // RNE (inputs finite)
    return (unsigned short)(u >> 16);
}

// packed f32x2 -> bf16x2 (v_cvt_pk_bf16_f32): low = a, high = b
static __device__ __forceinline__ unsigned pk2(float a, float b) {
    __hip_bfloat162 h = __float22bfloat162_rn(make_float2(a, b));
    return *(unsigned*)&h;
}

#define VC(vv,kk) ((kk)==0?(vv).x:((kk)==1?(vv).y:((kk)==2?(vv).z:(vv).w)))

// ---------------- Kernel W (fused mod + wmod):
// block (b, co), 64 threads (thread = ci). Computes s[b][ci] locally
// (512-MAC dot, mod_w L2-broadcast), then modulate + demod, emit bf16
// weights in 32x32 A-frag layout wbf[b][ko 9][g 8][co 64][j 8].
__global__ void wmod_fused(const float* __restrict__ style,
                           const float* __restrict__ mod_w,
                           const float* __restrict__ mod_b,
                           const float* __restrict__ weight,
                           unsigned short* __restrict__ wbf) {
    int bc = blockIdx.x;                // b*64 + co
    int b = bc >> 6, co = bc & 63;
    int ci = threadIdx.x;               // one wave

    // s[b][ci] = style[b,:] @ mod_w[:,ci] * lin_scale + mod_b[ci]
    const float* st = style + b * SS;
    float acc = 0.f;
    for (int k = 0; k < SS; ++k)
        acc = fmaf(st[k], mod_w[k * CC + ci], acc);
    float sv = (acc * LIN_SCALE + mod_b[ci]) * CONV_SCALE;

    float wv[9];
    float sum = 0.f;
    const float* wp = weight + (co * CC + ci) * 9;
#pragma unroll
    for (int k = 0; k < 9; ++k) {
        wv[k] = wp[k] * sv;
        sum = fmaf(wv[k], wv[k], sum);
    }
#pragma unroll
    for (int off = 32; off; off >>= 1)
        sum += __shfl_xor(sum, off);
    float demod = rsqrtf(sum + 1e-8f);
    int g = ci >> 3, j = ci & 7;
#pragma unroll
    for (int ko = 0; ko < 9; ++ko) {
        size_t idx = ((((size_t)b * 9 + ko) * 8 + g) * 64 + co) * 8 + j;
        wbf[idx] = f2bf(wv[ko] * demod);
    }
}

// ---------------- Kernel C: implicit-GEMM conv, MFMA 32x32x16 bf16 (R21)
// 256 thr (4 waves). Wave wv owns rows wv*2..wv*2+1 and ALL 64 co.
// A-ring + noise prefetched BEFORE staging (latency hides under stage).
// Staging: 2 batches of 2 tasks (16 loads in flight) -> 2 exposed latencies.
// A-frags from GLOBAL wbf (depth-2 ring); B-frags from xs LDS (contiguous).
__global__ __launch_bounds__(256, 3) void conv_kernel(
        const float* __restrict__ x,
        const float* __restrict__ noise,
        const float* __restrict__ nwp,
        const float* __restrict__ bias,
        const unsigned short* __restrict__ wbf,
        float* __restrict__ out) {
    __shared__ unsigned short xs[8 * LY * LX * 8];   // 43520 B

    // bijective XCD swizzle: XCD c -> batch image b=c (256 blocks per image)
    const int lin  = blockIdx.x;                 // 0..2047
    const int lin2 = (lin & 7) * 256 + (lin >> 3);
    const int b   = lin2 >> 8;
    const int rem = lin2 & 255;
    const int by  = rem >> 3;      // 0..31
    const int bx  = rem & 7;       // 0..7
    const int x0t = bx * TX;
    const int y0t = by * TY;

    const int t = threadIdx.x;
    const int lane = t & 63;
    const int wv = t >> 6;         // wave 0..3 -> row pair
    const int n31 = lane & 31;
    const int h   = lane >> 5;     // k-slice half

    // ---- early prefetch: A-ring (weights) + noise, independent of staging
    const unsigned short* wb = wbf + (size_t)b * WLE;
#define ALOAD(ko, kc, m) \
    (*(const short8*)&wb[((((ko) * 8 + (kc) * 2 + h) * 64) + (m) * 32 + n31) * 8])
    short8 a0c = ALOAD(0, 0, 0), a1c = ALOAD(0, 0, 1);
    short8 a0n = ALOAD(0, 1, 0), a1n = ALOAD(0, 1, 1);
    const float nw = nwp[0];
    float nzr0 = noise[(size_t)b * HW + (size_t)(y0t + wv * 2)     * WW + x0t + n31];
    float nzr1 = noise[(size_t)b * HW + (size_t)(y0t + wv * 2 + 1) * WW + x0t + n31];
    __builtin_amdgcn_sched_barrier(0);   // pin prefetches above staging

    // ---- stage x: 800 tasks; 2 batches x 2 tasks per thread
#pragma unroll
    for (int bt = 0; bt < 2; ++bt) {
        int na = t + bt * 512;  na = na < 799 ? na : 799;
        int nb = na + 256;      nb = nb < 799 ? nb : 799;

        int qa = na % 10, ra = na / 10, yla = ra % 10, ga = ra / 10;
        int qb = nb % 10, rb = nb / 10, ylb = rb % 10, gb = rb / 10;
        int gya = y0t + yla - 1, gyb = y0t + ylb - 1;
        int gx0a = x0t - 4 + qa * 4, gx0b = x0t - 4 + qb * 4;
        bool rowoka = (unsigned)gya < (unsigned)HH;
        bool rowokb = (unsigned)gyb < (unsigned)HH;
        int gyca  = gya < 0 ? 0 : (gya > HH - 1 ? HH - 1 : gya);
        int gycb  = gyb < 0 ? 0 : (gyb > HH - 1 ? HH - 1 : gyb);
        int gx0ca = gx0a < 0 ? 0 : (gx0a > WW - 4 ? WW - 4 : gx0a);
        int gx0cb = gx0b < 0 ? 0 : (gx0b > WW - 4 ? WW - 4 : gx0b);
        const float* xpa = x + ((size_t)b * CC + ga * 8) * HW + (size_t)gyca * WW + gx0ca;
        const float* xpb = x + ((size_t)b * CC + gb * 8) * HW + (size_t)gycb * WW + gx0cb;

        float4 va[8], vb2[8];
#pragma unroll
        for (int j = 0; j < 8; ++j) va[j]  = *(const float4*)(xpa + (size_t)j * HW);
#pragma unroll
        for (int j = 0; j < 8; ++j) vb2[j] = *(const float4*)(xpb + (size_t)j * HW);
        __builtin_amdgcn_sched_barrier(0);   // both load batches issued first

#pragma unroll
        for (int k = 0; k < 4; ++k) {
            int lx = 4 * qa - 3 + k;
            if ((unsigned)lx < (unsigned)LX) {
                bool ok = rowoka && ((unsigned)(gx0a + k) < (unsigned)WW);
                uint4 w;
                w.x = ok ? pk2(VC(va[0], k), VC(va[1], k)) : 0u;
                w.y = ok ? pk2(VC(va[2], k), VC(va[3], k)) : 0u;
                w.z = ok ? pk2(VC(va[4], k), VC(va[5], k)) : 0u;
                w.w = ok ? pk2(VC(va[6], k), VC(va[7], k)) : 0u;
                *(uint4*)&xs[((ga * LY + yla) * LX + lx) * 8] = w;
            }
        }
#pragma unroll
        for (int k = 0; k < 4; ++k) {
            int lx = 4 * qb - 3 + k;
            if ((unsigned)lx < (unsigned)LX) {
                bool ok = rowokb && ((unsigned)(gx0b + k) < (unsigned)WW);
                uint4 w;
                w.x = ok ? pk2(VC(vb2[0], k), VC(vb2[1], k)) : 0u;
                w.y = ok ? pk2(VC(vb2[2], k), VC(vb2[3], k)) : 0u;
                w.z = ok ? pk2(VC(vb2[4], k), VC(vb2[5], k)) : 0u;
                w.w = ok ? pk2(VC(vb2[6], k), VC(vb2[7], k)) : 0u;
                *(uint4*)&xs[((gb * LY + ylb) * LX + lx) * 8] = w;
            }
        }
    }
    __syncthreads();

    // ---- compute: A from global (depth-2 prefetch ring), B from LDS
    floatx16 acc[2][2];
    acc[0][0] = (floatx16)0.f; acc[0][1] = (floatx16)0.f;
    acc[1][0] = (floatx16)0.f; acc[1][1] = (floatx16)0.f;

#pragma unroll
    for (int ko = 0; ko < 9; ++ko) {
        const int kh = ko / 3, kw = ko % 3;
#pragma unroll
        for (int kc = 0; kc < 4; ++kc) {
            // prefetch step+2
            short8 p0 = a0n, p1 = a1n;
            {
                int s2 = ko * 4 + kc + 2;
                if (s2 <= 35) {
                    int pko = s2 >> 2, pkc = s2 & 3;
                    p0 = ALOAD(pko, pkc, 0);
                    p1 = ALOAD(pko, pkc, 1);
                }
            }
            const int g = kc * 2 + h;
#pragma unroll
            for (int rl = 0; rl < 2; ++rl) {
                int ys = wv * 2 + rl + kh;
                short8 bv = *(const short8*)&xs[((g * LY + ys) * LX + kw + n31) * 8];
                __builtin_amdgcn_s_setprio(1);
                acc[rl][0] = __builtin_amdgcn_mfma_f32_32x32x16_bf16(
                    a0c, bv, acc[rl][0], 0, 0, 0);
                acc[rl][1] = __builtin_amdgcn_mfma_f32_32x32x16_bf16(
                    a1c, bv, acc[rl][1], 0, 0, 0);
                __builtin_amdgcn_s_setprio(0);
            }
            a0c = a0n; a1c = a1n;
            a0n = p0;  a1n = p1;
        }
    }
#undef ALOAD

    // ---- epilogue: noise + bias + leaky_relu * gain
    // D layout (32x32): col px = lane&31, row co32 = (reg&3) + 8*(reg>>2) + 4*h
#pragma unroll
    for (int rl = 0; rl < 2; ++rl) {
        int py = y0t + wv * 2 + rl;
        float nz = nw * (rl ? nzr1 : nzr0);
#pragma unroll
        for (int reg = 0; reg < 16; ++reg) {
            int cr = (reg & 3) + 8 * (reg >> 2) + 4 * h;
            float v0 = acc[rl][0][reg] + nz + bias[cr];
            v0 = (v0 > 0.f ? v0 : LRELU * v0) * GAIN;
            out[((size_t)b * CC + cr) * HW + (size_t)py * WW + x0t + n31] = v0;
            float v1 = acc[rl][1][reg] + nz + bias[32 + cr];
            v1 = (v1 > 0.f ? v1 : LRELU * v1) * GAIN;
            out[((size_t)b * CC + 32 + cr) * HW + (size_t)py * WW + x0t + n31] = v1;
        }
    }
}

extern "C" void kernel_launch(void* const* d_in, const int* in_sizes, int n_in,
                              void* d_out, int out_size, void* d_ws, size_t ws_size,
                              hipStream_t stream) {
    const float* x       = (const float*)d_in[0];
    const float* style   = (const float*)d_in[1];
    const float* noise   = (const float*)d_in[2];
    const float* weight  = (const float*)d_in[3];
    const float* mod_w   = (const float*)d_in[4];
    const float* mod_b   = (const float*)d_in[5];
    const float* nw      = (const float*)d_in[6];
    const float* bias    = (const float*)d_in[7];
    float* out = (float*)d_out;

    unsigned short* wbf   = (unsigned short*)((char*)d_ws + 4096); // 576 KB

    wmod_fused<<<dim3(BB * CC), dim3(CC), 0, stream>>>(
        style, mod_w, mod_b, weight, wbf);
    conv_kernel<<<dim3((WW / TX) * (HH / TY) * BB), dim3(256), 0, stream>>>(
        x, noise, nw, bias, wbf, out);
}

// Round 24
// 82.894 us; speedup vs baseline: 2.0396x; 1.0535x over previous
//
#include <hip/hip_runtime.h>
#include <hip/hip_bf16.h>

// StyledConv: B=8, Cin=Cout=64, H=W=256, S=512, K=3
#define BB   8
#define CC   64
#define HH   256
#define WW   256
#define SS   512
#define HW   (HH*WW)

#define LIN_SCALE  0.044194173824159216f   // 1/sqrt(512)
#define CONV_SCALE 0.041666666666666664f   // 1/24
#define LRELU      0.2f
#define GAIN       1.4142135623730951f

// conv tile: 8 rows x 32 cols out, all 64 co, all 64 ci staged once
#define TY 8
#define TX 32
#define LY (TY + 2)   // 10
#define LX (TX + 2)   // 34
#define WLE (9 * 8 * 64 * 8)        // weight elems per image

typedef __attribute__((ext_vector_type(8)))  short short8;     // A/B frag (8 bf16)
typedef __attribute__((ext_vector_type(16))) float floatx16;   // 32x32 C/D frag

static __device__ __forceinline__ unsigned short f2bf(float f) {
    unsigned u = __float_as_uint(f);
    u += 0x7FFF + ((u >> 16) & 1);          // RNE (inputs finite)
    return (unsigned short)(u >> 16);
}

// packed f32x2 -> bf16x2 (v_cvt_pk_bf16_f32): low = a, high = b
static __device__ __forceinline__ unsigned pk2(float a, float b) {
    __hip_bfloat162 h = __float22bfloat162_rn(make_float2(a, b));
    return *(unsigned*)&h;
}

#define VC(vv,kk) ((kk)==0?(vv).x:((kk)==1?(vv).y:((kk)==2?(vv).z:(vv).w)))

// ---------------- Kernel A ----------------
__global__ void mod_kernel(const float* __restrict__ style,
                           const float* __restrict__ mod_w,
                           const float* __restrict__ mod_b,
                           float* __restrict__ s_out) {
    __shared__ float part[256];
    int b = blockIdx.x;
    int t = threadIdx.x;
    int ci = t & 63, kp = t >> 6;
    const float* st = style + b * SS + kp * 128;
    float acc = 0.f;
    for (int k = 0; k < 128; ++k)
        acc = fmaf(st[k], mod_w[(kp * 128 + k) * CC + ci], acc);
    part[t] = acc;
    __syncthreads();
    if (t < 64) {
        float v = part[t] + part[t + 64] + part[t + 128] + part[t + 192];
        s_out[b * CC + t] = v * LIN_SCALE + mod_b[t];
    }
}

// ---------------- Kernel B: weights -> wbf[b][ko 9][g 8][co 64][j 8] ----------------
__global__ void wmod_kernel(const float* __restrict__ weight,
                            const float* __restrict__ s_in,
                            unsigned short* __restrict__ wbf) {
    int bc = blockIdx.x;                // b*64 + co
    int b = bc >> 6, co = bc & 63;
    int ci = threadIdx.x;               // one wave
    float wv[9];
    float sv = s_in[b * CC + ci] * CONV_SCALE;
    float sum = 0.f;
    const float* wp = weight + (co * CC + ci) * 9;
#pragma unroll
    for (int k = 0; k < 9; ++k) {
        wv[k] = wp[k] * sv;
        sum = fmaf(wv[k], wv[k], sum);
    }
#pragma unroll
    for (int off = 32; off; off >>= 1)
        sum += __shfl_xor(sum, off);
    float demod = rsqrtf(sum + 1e-8f);
    int g = ci >> 3, j = ci & 7;
#pragma unroll
    for (int ko = 0; ko < 9; ++ko) {
        size_t idx = ((((size_t)b * 9 + ko) * 8 + g) * 64 + co) * 8 + j;
        wbf[idx] = f2bf(wv[ko] * demod);
    }
}

// ---------------- Kernel C: implicit-GEMM conv, MFMA 32x32x16 bf16
// 256 thr (4 waves). Wave wv owns rows wv*2..wv*2+1 and ALL 64 co.
// A-ring + noise prefetched BEFORE staging (latency hides under stage).
// Staging: 2 batches of 2 tasks (16 loads in flight) -> 2 exposed latencies.
// A-frags from GLOBAL wbf (depth-2 ring); B-frags from xs LDS (contiguous).
__global__ __launch_bounds__(256, 3) void conv_kernel(
        const float* __restrict__ x,
        const float* __restrict__ noise,
        const float* __restrict__ nwp,
        const float* __restrict__ bias,
        const unsigned short* __restrict__ wbf,
        float* __restrict__ out) {
    __shared__ unsigned short xs[8 * LY * LX * 8];   // 43520 B

    // bijective XCD swizzle: XCD c -> batch image b=c (256 blocks per image)
    const int lin  = blockIdx.x;                 // 0..2047
    const int lin2 = (lin & 7) * 256 + (lin >> 3);
    const int b   = lin2 >> 8;
    const int rem = lin2 & 255;
    const int by  = rem >> 3;      // 0..31
    const int bx  = rem & 7;       // 0..7
    const int x0t = bx * TX;
    const int y0t = by * TY;

    const int t = threadIdx.x;
    const int lane = t & 63;
    const int wv = t >> 6;         // wave 0..3 -> row pair
    const int n31 = lane & 31;
    const int h   = lane >> 5;     // k-slice half

    // ---- early prefetch: A-ring (weights) + noise, independent of staging
    const unsigned short* wb = wbf + (size_t)b * WLE;
#define ALOAD(ko, kc, m) \
    (*(const short8*)&wb[((((ko) * 8 + (kc) * 2 + h) * 64) + (m) * 32 + n31) * 8])
    short8 a0c = ALOAD(0, 0, 0), a1c = ALOAD(0, 0, 1);
    short8 a0n = ALOAD(0, 1, 0), a1n = ALOAD(0, 1, 1);
    const float nw = nwp[0];
    float nzr0 = noise[(size_t)b * HW + (size_t)(y0t + wv * 2)     * WW + x0t + n31];
    float nzr1 = noise[(size_t)b * HW + (size_t)(y0t + wv * 2 + 1) * WW + x0t + n31];
    __builtin_amdgcn_sched_barrier(0);   // pin prefetches above staging

    // ---- stage x: 800 tasks; 2 batches x 2 tasks per thread
#pragma unroll
    for (int bt = 0; bt < 2; ++bt) {
        int na = t + bt * 512;  na = na < 799 ? na : 799;
        int nb = na + 256;      nb = nb < 799 ? nb : 799;

        int qa = na % 10, ra = na / 10, yla = ra % 10, ga = ra / 10;
        int qb = nb % 10, rb = nb / 10, ylb = rb % 10, gb = rb / 10;
        int gya = y0t + yla - 1, gyb = y0t + ylb - 1;
        int gx0a = x0t - 4 + qa * 4, gx0b = x0t - 4 + qb * 4;
        bool rowoka = (unsigned)gya < (unsigned)HH;
        bool rowokb = (unsigned)gyb < (unsigned)HH;
        int gyca  = gya < 0 ? 0 : (gya > HH - 1 ? HH - 1 : gya);
        int gycb  = gyb < 0 ? 0 : (gyb > HH - 1 ? HH - 1 : gyb);
        int gx0ca = gx0a < 0 ? 0 : (gx0a > WW - 4 ? WW - 4 : gx0a);
        int gx0cb = gx0b < 0 ? 0 : (gx0b > WW - 4 ? WW - 4 : gx0b);
        const float* xpa = x + ((size_t)b * CC + ga * 8) * HW + (size_t)gyca * WW + gx0ca;
        const float* xpb = x + ((size_t)b * CC + gb * 8) * HW + (size_t)gycb * WW + gx0cb;

        float4 va[8], vb2[8];
#pragma unroll
        for (int j = 0; j < 8; ++j) va[j]  = *(const float4*)(xpa + (size_t)j * HW);
#pragma unroll
        for (int j = 0; j < 8; ++j) vb2[j] = *(const float4*)(xpb + (size_t)j * HW);
        __builtin_amdgcn_sched_barrier(0);   // both load batches issued first

#pragma unroll
        for (int k = 0; k < 4; ++k) {
            int lx = 4 * qa - 3 + k;
            if ((unsigned)lx < (unsigned)LX) {
                bool ok = rowoka && ((unsigned)(gx0a + k) < (unsigned)WW);
                uint4 w;
                w.x = ok ? pk2(VC(va[0], k), VC(va[1], k)) : 0u;
                w.y = ok ? pk2(VC(va[2], k), VC(va[3], k)) : 0u;
                w.z = ok ? pk2(VC(va[4], k), VC(va[5], k)) : 0u;
                w.w = ok ? pk2(VC(va[6], k), VC(va[7], k)) : 0u;
                *(uint4*)&xs[((ga * LY + yla) * LX + lx) * 8] = w;
            }
        }
#pragma unroll
        for (int k = 0; k < 4; ++k) {
            int lx = 4 * qb - 3 + k;
            if ((unsigned)lx < (unsigned)LX) {
                bool ok = rowokb && ((unsigned)(gx0b + k) < (unsigned)WW);
                uint4 w;
                w.x = ok ? pk2(VC(vb2[0], k), VC(vb2[1], k)) : 0u;
                w.y = ok ? pk2(VC(vb2[2], k), VC(vb2[3], k)) : 0u;
                w.z = ok ? pk2(VC(vb2[4], k), VC(vb2[5], k)) : 0u;
                w.w = ok ? pk2(VC(vb2[6], k), VC(vb2[7], k)) : 0u;
                *(uint4*)&xs[((gb * LY + ylb) * LX + lx) * 8] = w;
            }
        }
    }
    __syncthreads();

    // ---- compute: A from global (depth-2 prefetch ring), B from LDS
    floatx16 acc[2][2];
    acc[0][0] = (floatx16)0.f; acc[0][1] = (floatx16)0.f;
    acc[1][0] = (floatx16)0.f; acc[1][1] = (floatx16)0.f;

#pragma unroll
    for (int ko = 0; ko < 9; ++ko) {
        const int kh = ko / 3, kw = ko % 3;
#pragma unroll
        for (int kc = 0; kc < 4; ++kc) {
            // prefetch step+2
            short8 p0 = a0n, p1 = a1n;
            {
                int s2 = ko * 4 + kc + 2;
                if (s2 <= 35) {
                    int pko = s2 >> 2, pkc = s2 & 3;
                    p0 = ALOAD(pko, pkc, 0);
                    p1 = ALOAD(pko, pkc, 1);
                }
            }
            const int g = kc * 2 + h;
#pragma unroll
            for (int rl = 0; rl < 2; ++rl) {
                int ys = wv * 2 + rl + kh;
                short8 bv = *(const short8*)&xs[((g * LY + ys) * LX + kw + n31) * 8];
                __builtin_amdgcn_s_setprio(1);
                acc[rl][0] = __builtin_amdgcn_mfma_f32_32x32x16_bf16(
                    a0c, bv, acc[rl][0], 0, 0, 0);
                acc[rl][1] = __builtin_amdgcn_mfma_f32_32x32x16_bf16(
                    a1c, bv, acc[rl][1], 0, 0, 0);
                __builtin_amdgcn_s_setprio(0);
            }
            a0c = a0n; a1c = a1n;
            a0n = p0;  a1n = p1;
        }
    }
#undef ALOAD

    // ---- epilogue: noise + bias + leaky_relu * gain
    // D layout (32x32): col px = lane&31, row co32 = (reg&3) + 8*(reg>>2) + 4*h
#pragma unroll
    for (int rl = 0; rl < 2; ++rl) {
        int py = y0t + wv * 2 + rl;
        float nz = nw * (rl ? nzr1 : nzr0);
#pragma unroll
        for (int reg = 0; reg < 16; ++reg) {
            int cr = (reg & 3) + 8 * (reg >> 2) + 4 * h;
            float v0 = acc[rl][0][reg] + nz + bias[cr];
            v0 = (v0 > 0.f ? v0 : LRELU * v0) * GAIN;
            out[((size_t)b * CC + cr) * HW + (size_t)py * WW + x0t + n31] = v0;
            float v1 = acc[rl][1][reg] + nz + bias[32 + cr];
            v1 = (v1 > 0.f ? v1 : LRELU * v1) * GAIN;
            out[((size_t)b * CC + 32 + cr) * HW + (size_t)py * WW + x0t + n31] = v1;
        }
    }
}

extern "C" void kernel_launch(void* const* d_in, const int* in_sizes, int n_in,
                              void* d_out, int out_size, void* d_ws, size_t ws_size,
                              hipStream_t stream) {
    const float* x       = (const float*)d_in[0];
    const float* style   = (const float*)d_in[1];
    const float* noise   = (const float*)d_in[2];
    const float* weight  = (const float*)d_in[3];
    const float* mod_w   = (const float*)d_in[4];
    const float* mod_b   = (const float*)d_in[5];
    const float* nw      = (const float*)d_in[6];
    const float* bias    = (const float*)d_in[7];
    float* out = (float*)d_out;

    float* s_buf          = (float*)d_ws;                          // 2 KB
    unsigned short* wbf   = (unsigned short*)((char*)d_ws + 4096); // 576 KB

    mod_kernel<<<dim3(BB), dim3(256), 0, stream>>>(style, mod_w, mod_b, s_buf);
    wmod_kernel<<<dim3(BB * CC), dim3(CC), 0, stream>>>(weight, s_buf, wbf);
    conv_kernel<<<dim3((WW / TX) * (HH / TY) * BB), dim3(256), 0, stream>>>(
        x, noise, nw, bias, wbf, out);
}

// Round 25
// 81.377 us; speedup vs baseline: 2.0776x; 1.0186x over previous
//
#include <hip/hip_runtime.h>
#include <hip/hip_bf16.h>

// StyledConv: B=8, Cin=Cout=64, H=W=256, S=512, K=3
#define BB   8
#define CC   64
#define HH   256
#define WW   256
#define SS   512
#define HW   (HH*WW)

#define LIN_SCALE  0.044194173824159216f   // 1/sqrt(512)
#define CONV_SCALE 0.041666666666666664f   // 1/24
#define LRELU      0.2f
#define GAIN       1.4142135623730951f

// conv tile: 8 rows x 32 cols out, all 64 co, all 64 ci staged once
#define TY 8
#define TX 32
#define LY (TY + 2)   // 10
#define LX (TX + 2)   // 34
#define WLE (9 * 8 * 64 * 8)        // weight elems per image

typedef __attribute__((ext_vector_type(8)))  short short8;     // A/B frag (8 bf16)
typedef __attribute__((ext_vector_type(16))) float floatx16;   // 32x32 C/D frag

static __device__ __forceinline__ unsigned short f2bf(float f) {
    unsigned u = __float_as_uint(f);
    u += 0x7FFF + ((u >> 16) & 1);          // RNE (inputs finite)
    return (unsigned short)(u >> 16);
}

// packed f32x2 -> bf16x2 (v_cvt_pk_bf16_f32): low = a, high = b
static __device__ __forceinline__ unsigned pk2(float a, float b) {
    __hip_bfloat162 h = __float22bfloat162_rn(make_float2(a, b));
    return *(unsigned*)&h;
}

#define VC(vv,kk) ((kk)==0?(vv).x:((kk)==1?(vv).y:((kk)==2?(vv).z:(vv).w)))

// ---------------- Kernel P: fused prep (mod + wmod), ONE launch
// grid = 64 blocks: b (8) x co-group-of-8 (8). 256 threads.
// Phase 1: s[b][ci] via 4-way k-split + tree reduce (same structure as R21's
// mod_kernel -> identical numerics). 8x redundant across co-groups (trivial).
// Phase 2: wmod for this block's 8 co (2 per wave, lane = ci).
// Output: wbf[b][ko 9][g 8][co 64][j 8] (32x32 A-frag layout).
__global__ void prep_kernel(const float* __restrict__ style,
                            const float* __restrict__ mod_w,
                            const float* __restrict__ mod_b,
                            const float* __restrict__ weight,
                            unsigned short* __restrict__ wbf) {
    __shared__ float part[256];
    __shared__ float s_l[64];
    const int blk = blockIdx.x;       // b*8 + cog
    const int b = blk >> 3, cog = blk & 7;
    const int t = threadIdx.x;

    // ---- phase 1: s (parallel dot: 4-way k-split over 256 threads)
    {
        int ci = t & 63, kp = t >> 6;
        const float* st = style + b * SS + kp * 128;
        float acc = 0.f;
        for (int k = 0; k < 128; ++k)
            acc = fmaf(st[k], mod_w[(kp * 128 + k) * CC + ci], acc);
        part[t] = acc;
    }
    __syncthreads();
    if (t < 64) {
        float v = part[t] + part[t + 64] + part[t + 128] + part[t + 192];
        s_l[t] = (v * LIN_SCALE + mod_b[t]) * CONV_SCALE;
    }
    __syncthreads();

    // ---- phase 2: wmod for co = cog*8 + wv*2 + {0,1}; lane = ci
    const int wv = t >> 6;
    const int ci = t & 63;
    const float sv = s_l[ci];
    const int g = ci >> 3, j = ci & 7;
#pragma unroll
    for (int cc = 0; cc < 2; ++cc) {
        int co = cog * 8 + wv * 2 + cc;
        float wvv[9];
        float sum = 0.f;
        const float* wp = weight + (co * CC + ci) * 9;
#pragma unroll
        for (int k = 0; k < 9; ++k) {
            wvv[k] = wp[k] * sv;
            sum = fmaf(wvv[k], wvv[k], sum);
        }
#pragma unroll
        for (int off = 32; off; off >>= 1)
            sum += __shfl_xor(sum, off);
        float demod = rsqrtf(sum + 1e-8f);
#pragma unroll
        for (int ko = 0; ko < 9; ++ko) {
            size_t idx = ((((size_t)b * 9 + ko) * 8 + g) * 64 + co) * 8 + j;
            wbf[idx] = f2bf(wvv[ko] * demod);
        }
    }
}

// ---------------- Kernel C: implicit-GEMM conv, MFMA 32x32x16 bf16 (R21)
// 256 thr (4 waves). Wave wv owns rows wv*2..wv*2+1 and ALL 64 co.
// A-ring + noise prefetched BEFORE staging (latency hides under stage).
// Staging: 2 batches of 2 tasks (16 loads in flight) -> 2 exposed latencies.
// A-frags from GLOBAL wbf (depth-2 ring); B-frags from xs LDS (contiguous).
__global__ __launch_bounds__(256, 3) void conv_kernel(
        const float* __restrict__ x,
        const float* __restrict__ noise,
        const float* __restrict__ nwp,
        const float* __restrict__ bias,
        const unsigned short* __restrict__ wbf,
        float* __restrict__ out) {
    __shared__ unsigned short xs[8 * LY * LX * 8];   // 43520 B

    // bijective XCD swizzle: XCD c -> batch image b=c (256 blocks per image)
    const int lin  = blockIdx.x;                 // 0..2047
    const int lin2 = (lin & 7) * 256 + (lin >> 3);
    const int b   = lin2 >> 8;
    const int rem = lin2 & 255;
    const int by  = rem >> 3;      // 0..31
    const int bx  = rem & 7;       // 0..7
    const int x0t = bx * TX;
    const int y0t = by * TY;

    const int t = threadIdx.x;
    const int lane = t & 63;
    const int wv = t >> 6;         // wave 0..3 -> row pair
    const int n31 = lane & 31;
    const int h   = lane >> 5;     // k-slice half

    // ---- early prefetch: A-ring (weights) + noise, independent of staging
    const unsigned short* wb = wbf + (size_t)b * WLE;
#define ALOAD(ko, kc, m) \
    (*(const short8*)&wb[((((ko) * 8 + (kc) * 2 + h) * 64) + (m) * 32 + n31) * 8])
    short8 a0c = ALOAD(0, 0, 0), a1c = ALOAD(0, 0, 1);
    short8 a0n = ALOAD(0, 1, 0), a1n = ALOAD(0, 1, 1);
    const float nw = nwp[0];
    float nzr0 = noise[(size_t)b * HW + (size_t)(y0t + wv * 2)     * WW + x0t + n31];
    float nzr1 = noise[(size_t)b * HW + (size_t)(y0t + wv * 2 + 1) * WW + x0t + n31];
    __builtin_amdgcn_sched_barrier(0);   // pin prefetches above staging

    // ---- stage x: 800 tasks; 2 batches x 2 tasks per thread
#pragma unroll
    for (int bt = 0; bt < 2; ++bt) {
        int na = t + bt * 512;  na = na < 799 ? na : 799;
        int nb = na + 256;      nb = nb < 799 ? nb : 799;

        int qa = na % 10, ra = na / 10, yla = ra % 10, ga = ra / 10;
        int qb = nb % 10, rb = nb / 10, ylb = rb % 10, gb = rb / 10;
        int gya = y0t + yla - 1, gyb = y0t + ylb - 1;
        int gx0a = x0t - 4 + qa * 4, gx0b = x0t - 4 + qb * 4;
        bool rowoka = (unsigned)gya < (unsigned)HH;
        bool rowokb = (unsigned)gyb < (unsigned)HH;
        int gyca  = gya < 0 ? 0 : (gya > HH - 1 ? HH - 1 : gya);
        int gycb  = gyb < 0 ? 0 : (gyb > HH - 1 ? HH - 1 : gyb);
        int gx0ca = gx0a < 0 ? 0 : (gx0a > WW - 4 ? WW - 4 : gx0a);
        int gx0cb = gx0b < 0 ? 0 : (gx0b > WW - 4 ? WW - 4 : gx0b);
        const float* xpa = x + ((size_t)b * CC + ga * 8) * HW + (size_t)gyca * WW + gx0ca;
        const float* xpb = x + ((size_t)b * CC + gb * 8) * HW + (size_t)gycb * WW + gx0cb;

        float4 va[8], vb2[8];
#pragma unroll
        for (int j = 0; j < 8; ++j) va[j]  = *(const float4*)(xpa + (size_t)j * HW);
#pragma unroll
        for (int j = 0; j < 8; ++j) vb2[j] = *(const float4*)(xpb + (size_t)j * HW);
        __builtin_amdgcn_sched_barrier(0);   // both load batches issued first

#pragma unroll
        for (int k = 0; k < 4; ++k) {
            int lx = 4 * qa - 3 + k;
            if ((unsigned)lx < (unsigned)LX) {
                bool ok = rowoka && ((unsigned)(gx0a + k) < (unsigned)WW);
                uint4 w;
                w.x = ok ? pk2(VC(va[0], k), VC(va[1], k)) : 0u;
                w.y = ok ? pk2(VC(va[2], k), VC(va[3], k)) : 0u;
                w.z = ok ? pk2(VC(va[4], k), VC(va[5], k)) : 0u;
                w.w = ok ? pk2(VC(va[6], k), VC(va[7], k)) : 0u;
                *(uint4*)&xs[((ga * LY + yla) * LX + lx) * 8] = w;
            }
        }
#pragma unroll
        for (int k = 0; k < 4; ++k) {
            int lx = 4 * qb - 3 + k;
            if ((unsigned)lx < (unsigned)LX) {
                bool ok = rowokb && ((unsigned)(gx0b + k) < (unsigned)WW);
                uint4 w;
                w.x = ok ? pk2(VC(vb2[0], k), VC(vb2[1], k)) : 0u;
                w.y = ok ? pk2(VC(vb2[2], k), VC(vb2[3], k)) : 0u;
                w.z = ok ? pk2(VC(vb2[4], k), VC(vb2[5], k)) : 0u;
                w.w = ok ? pk2(VC(vb2[6], k), VC(vb2[7], k)) : 0u;
                *(uint4*)&xs[((gb * LY + ylb) * LX + lx) * 8] = w;
            }
        }
    }
    __syncthreads();

    // ---- compute: A from global (depth-2 prefetch ring), B from LDS
    floatx16 acc[2][2];
    acc[0][0] = (floatx16)0.f; acc[0][1] = (floatx16)0.f;
    acc[1][0] = (floatx16)0.f; acc[1][1] = (floatx16)0.f;

#pragma unroll
    for (int ko = 0; ko < 9; ++ko) {
        const int kh = ko / 3, kw = ko % 3;
#pragma unroll
        for (int kc = 0; kc < 4; ++kc) {
            // prefetch step+2
            short8 p0 = a0n, p1 = a1n;
            {
                int s2 = ko * 4 + kc + 2;
                if (s2 <= 35) {
                    int pko = s2 >> 2, pkc = s2 & 3;
                    p0 = ALOAD(pko, pkc, 0);
                    p1 = ALOAD(pko, pkc, 1);
                }
            }
            const int g = kc * 2 + h;
#pragma unroll
            for (int rl = 0; rl < 2; ++rl) {
                int ys = wv * 2 + rl + kh;
                short8 bv = *(const short8*)&xs[((g * LY + ys) * LX + kw + n31) * 8];
                __builtin_amdgcn_s_setprio(1);
                acc[rl][0] = __builtin_amdgcn_mfma_f32_32x32x16_bf16(
                    a0c, bv, acc[rl][0], 0, 0, 0);
                acc[rl][1] = __builtin_amdgcn_mfma_f32_32x32x16_bf16(
                    a1c, bv, acc[rl][1], 0, 0, 0);
                __builtin_amdgcn_s_setprio(0);
            }
            a0c = a0n; a1c = a1n;
            a0n = p0;  a1n = p1;
        }
    }
#undef ALOAD

    // ---- epilogue: noise + bias + leaky_relu * gain
    // D layout (32x32): col px = lane&31, row co32 = (reg&3) + 8*(reg>>2) + 4*h
#pragma unroll
    for (int rl = 0; rl < 2; ++rl) {
        int py = y0t + wv * 2 + rl;
        float nz = nw * (rl ? nzr1 : nzr0);
#pragma unroll
        for (int reg = 0; reg < 16; ++reg) {
            int cr = (reg & 3) + 8 * (reg >> 2) + 4 * h;
            float v0 = acc[rl][0][reg] + nz + bias[cr];
            v0 = (v0 > 0.f ? v0 : LRELU * v0) * GAIN;
            out[((size_t)b * CC + cr) * HW + (size_t)py * WW + x0t + n31] = v0;
            float v1 = acc[rl][1][reg] + nz + bias[32 + cr];
            v1 = (v1 > 0.f ? v1 : LRELU * v1) * GAIN;
            out[((size_t)b * CC + 32 + cr) * HW + (size_t)py * WW + x0t + n31] = v1;
        }
    }
}

extern "C" void kernel_launch(void* const* d_in, const int* in_sizes, int n_in,
                              void* d_out, int out_size, void* d_ws, size_t ws_size,
                              hipStream_t stream) {
    const float* x       = (const float*)d_in[0];
    const float* style   = (const float*)d_in[1];
    const float* noise   = (const float*)d_in[2];
    const float* weight  = (const float*)d_in[3];
    const float* mod_w   = (const float*)d_in[4];
    const float* mod_b   = (const float*)d_in[5];
    const float* nw      = (const float*)d_in[6];
    const float* bias    = (const float*)d_in[7];
    float* out = (float*)d_out;

    unsigned short* wbf   = (unsigned short*)((char*)d_ws + 4096); // 576 KB

    prep_kernel<<<dim3(BB * 8), dim3(256), 0, stream>>>(
        style, mod_w, mod_b, weight, wbf);
    conv_kernel<<<dim3((WW / TX) * (HH / TY) * BB), dim3(256), 0, stream>>>(
        x, noise, nw, bias, wbf, out);
}